// Round 1
// baseline (532.919 us; speedup 1.0000x reference)
//
#include <hip/hip_runtime.h>
#include <math.h>

#define DIN 128
#define DH  64
#define DOUT 16

// ---------------- degree count ----------------
__global__ __launch_bounds__(256) void deg_kernel(const int* __restrict__ dst,
                                                  int* __restrict__ counts, int E) {
    int e = blockIdx.x * 256 + threadIdx.x;
    if (e < E) atomicAdd(&counts[dst[e]], 1);
}

// ---------------- dinv = rsqrt(deg + selfloop) ----------------
__global__ __launch_bounds__(256) void dinv_kernel(const int* __restrict__ counts,
                                                   float* __restrict__ dinv, int n) {
    int i = blockIdx.x * 256 + threadIdx.x;
    if (i < n) dinv[i] = rsqrtf((float)(counts[i] + 1));
}

// ---------------- exclusive scan (single block, 1024 threads) ----------------
__global__ __launch_bounds__(1024) void scan_kernel(const int* __restrict__ counts,
                                                    int* __restrict__ offs, int n) {
    __shared__ int wsum[16];
    __shared__ int carry;
    int tid = threadIdx.x, lane = tid & 63, w = tid >> 6;
    if (tid == 0) carry = 0;
    __syncthreads();
    for (int base = 0; base < n; base += 1024) {
        int i = base + tid;
        int c = (i < n) ? counts[i] : 0;
        int v = c;
        #pragma unroll
        for (int d = 1; d < 64; d <<= 1) {
            int t = __shfl_up(v, d, 64);
            if (lane >= d) v += t;
        }
        if (lane == 63) wsum[w] = v;
        __syncthreads();
        if (w == 0) {
            int s = (lane < 16) ? wsum[lane] : 0;
            #pragma unroll
            for (int d = 1; d < 16; d <<= 1) {
                int t = __shfl_up(s, d, 64);
                if (lane >= d) s += t;
            }
            if (lane < 16) wsum[lane] = s;
        }
        __syncthreads();
        int wbase = (w == 0) ? 0 : wsum[w - 1];
        if (i < n) offs[i] = carry + wbase + v - c;
        __syncthreads();
        if (tid == 1023) carry += wsum[15];
        __syncthreads();
    }
    if (threadIdx.x == 0) offs[n] = carry;
}

// ---------------- scatter edges into CSR buckets ----------------
__global__ __launch_bounds__(256) void scatter_kernel(const int* __restrict__ src,
                                                      const int* __restrict__ dst,
                                                      const int* __restrict__ offs,
                                                      int* __restrict__ cursor,
                                                      const float* __restrict__ dinv,
                                                      int* __restrict__ csr_src,
                                                      float* __restrict__ csr_val, int E) {
    int e = blockIdx.x * 256 + threadIdx.x;
    if (e >= E) return;
    int d = dst[e];
    int s = src[e];
    int pos = atomicAdd(&cursor[d], 1);
    int j = offs[d] + pos;
    csr_src[j] = s;
    csr_val[j] = dinv[s];
}

// ---------------- dense matmul T[n,64] = H[n,K] @ W[K,64] ----------------
// Block: 256 threads = 4 waves; block handles 16 rows (4 per wave).
template <int K>
__global__ __launch_bounds__(256) void mm_kernel(const float* __restrict__ H,
                                                 const float* __restrict__ W,
                                                 float* __restrict__ T, int n) {
    __shared__ float wl[K * 64];
    __shared__ float hl[K][16];
    int tid = threadIdx.x;
    int row0 = blockIdx.x * 16;
    for (int i = tid; i < K * 64; i += 256) wl[i] = W[i];
    // stage 16 rows transposed: hl[k][r]; i = k*16 + r -> conflict-free LDS writes
    for (int i = tid; i < 16 * K; i += 256) {
        int r = i & 15;
        int k = i >> 4;
        int rr = row0 + r;
        hl[k][r] = (rr < n) ? H[(size_t)rr * K + k] : 0.f;
    }
    __syncthreads();
    int col = tid & 63;
    int w4 = (tid >> 6) * 4;  // this wave's first row within the block
    float acc0 = 0.f, acc1 = 0.f, acc2 = 0.f, acc3 = 0.f;
    #pragma unroll 8
    for (int k = 0; k < K; ++k) {
        float wv = wl[k * 64 + col];
        const float4 h4 = *reinterpret_cast<const float4*>(&hl[k][w4]);
        acc0 += h4.x * wv;
        acc1 += h4.y * wv;
        acc2 += h4.z * wv;
        acc3 += h4.w * wv;
    }
    int r0 = row0 + w4;
    if (r0 + 0 < n) T[(size_t)(r0 + 0) * 64 + col] = acc0;
    if (r0 + 1 < n) T[(size_t)(r0 + 1) * 64 + col] = acc1;
    if (r0 + 2 < n) T[(size_t)(r0 + 2) * 64 + col] = acc2;
    if (r0 + 3 < n) T[(size_t)(r0 + 3) * 64 + col] = acc3;
}

// ---------------- aggregation: wave per node, lane = feature dim ----------------
__global__ __launch_bounds__(256) void agg_kernel(const float* __restrict__ T,
                                                  const int* __restrict__ offs,
                                                  const int* __restrict__ csr_src,
                                                  const float* __restrict__ csr_val,
                                                  const float* __restrict__ dinv,
                                                  const float* __restrict__ bias,
                                                  float* __restrict__ Hout, int n) {
    int wid = (blockIdx.x * 256 + threadIdx.x) >> 6;
    int lane = threadIdx.x & 63;
    if (wid >= n) return;
    float di = dinv[wid];
    float acc = T[(size_t)wid * 64 + lane] * di;  // self loop (x di again below)
    int e0 = offs[wid], e1 = offs[wid + 1];
    for (int e = e0; e < e1; ++e) {
        int s = csr_src[e];
        float v = csr_val[e];
        acc += T[(size_t)s * 64 + lane] * v;
    }
    acc = acc * di + bias[lane];
    Hout[(size_t)wid * 64 + lane] = acc > 0.f ? acc : (expf(acc) - 1.f);  // ELU
}

// ---------------- final FC + softmax: 16 threads per node ----------------
__global__ __launch_bounds__(256) void final_kernel(const float* __restrict__ H,
                                                    const float* __restrict__ fcw,
                                                    const float* __restrict__ fcb,
                                                    float* __restrict__ out, int n) {
    __shared__ float wl[64 * 16];
    int tid = threadIdx.x;
    for (int i = tid; i < 64 * 16; i += 256) wl[i] = fcw[i];
    __syncthreads();
    int node = blockIdx.x * 16 + (tid >> 4);
    int j = tid & 15;
    if (node >= n) return;
    const float* hrow = H + (size_t)node * 64;
    float acc = fcb[j];
    #pragma unroll
    for (int k = 0; k < 64; ++k) acc += hrow[k] * wl[k * 16 + j];
    float m = acc;
    #pragma unroll
    for (int d = 8; d; d >>= 1) m = fmaxf(m, __shfl_xor(m, d, 16));
    float e = expf(acc - m);
    float s = e;
    #pragma unroll
    for (int d = 8; d; d >>= 1) s += __shfl_xor(s, d, 16);
    out[(size_t)node * 16 + j] = e / s;
}

extern "C" void kernel_launch(void* const* d_in, const int* in_sizes, int n_in,
                              void* d_out, int out_size, void* d_ws, size_t ws_size,
                              hipStream_t stream) {
    const float* x   = (const float*)d_in[0];
    const int*   ei  = (const int*)d_in[1];
    const float* w0  = (const float*)d_in[2];
    const float* b0  = (const float*)d_in[3];
    const float* w1  = (const float*)d_in[4];
    const float* b1  = (const float*)d_in[5];
    const float* w2  = (const float*)d_in[6];
    const float* b2  = (const float*)d_in[7];
    const float* fcw = (const float*)d_in[8];
    const float* fcb = (const float*)d_in[9];
    float* out = (float*)d_out;

    const int N = in_sizes[0] / DIN;
    const int E = in_sizes[1] / 2;
    const int* src = ei;
    const int* dst = ei + E;

    char* p = (char*)d_ws;
    auto take = [&](size_t bytes) {
        char* q = p;
        p += (bytes + 255) & ~(size_t)255;
        return q;
    };
    int*   counts  = (int*)take((size_t)N * 4);
    int*   cursor  = (int*)take((size_t)N * 4);
    int*   offs    = (int*)take((size_t)(N + 1) * 4);
    float* dinv    = (float*)take((size_t)N * 4);
    int*   csr_src = (int*)take((size_t)E * 4);
    float* csr_val = (float*)take((size_t)E * 4);
    float* tbuf    = (float*)take((size_t)N * DH * 4);
    float* hbuf    = (float*)take((size_t)N * DH * 4);

    hipMemsetAsync(counts, 0, (size_t)N * 4, stream);
    hipMemsetAsync(cursor, 0, (size_t)N * 4, stream);

    deg_kernel<<<(E + 255) / 256, 256, 0, stream>>>(dst, counts, E);
    dinv_kernel<<<(N + 255) / 256, 256, 0, stream>>>(counts, dinv, N);
    scan_kernel<<<1, 1024, 0, stream>>>(counts, offs, N);
    scatter_kernel<<<(E + 255) / 256, 256, 0, stream>>>(src, dst, offs, cursor, dinv,
                                                        csr_src, csr_val, E);

    int mm_grid  = (N + 15) / 16;
    int agg_grid = ((size_t)N * 64 + 255) / 256;

    // layer 0: x[N,128] @ w0 -> aggregate -> elu -> hbuf
    mm_kernel<DIN><<<mm_grid, 256, 0, stream>>>(x, w0, tbuf, N);
    agg_kernel<<<agg_grid, 256, 0, stream>>>(tbuf, offs, csr_src, csr_val, dinv, b0, hbuf, N);
    // layer 1
    mm_kernel<DH><<<mm_grid, 256, 0, stream>>>(hbuf, w1, tbuf, N);
    agg_kernel<<<agg_grid, 256, 0, stream>>>(tbuf, offs, csr_src, csr_val, dinv, b1, hbuf, N);
    // layer 2
    mm_kernel<DH><<<mm_grid, 256, 0, stream>>>(hbuf, w2, tbuf, N);
    agg_kernel<<<agg_grid, 256, 0, stream>>>(tbuf, offs, csr_src, csr_val, dinv, b2, hbuf, N);
    // FC + softmax
    final_kernel<<<mm_grid, 256, 0, stream>>>(hbuf, fcw, fcb, out, N);
}

// Round 2
// 394.003 us; speedup vs baseline: 1.3526x; 1.3526x over previous
//
#include <hip/hip_runtime.h>
#include <math.h>

#define DIN 128
#define DH  64
#define DOUT 16

// ---------------- degree count (in-degree) ----------------
__global__ __launch_bounds__(256) void deg_kernel(const int* __restrict__ dst,
                                                  int* __restrict__ counts, int E) {
    int e = blockIdx.x * 256 + threadIdx.x;
    if (e < E) atomicAdd(&counts[dst[e]], 1);
}

// ---------------- bucket alloc: offs via atomic bump (order irrelevant) ----------------
// Also computes dinv = rsqrt(deg+1) and initializes the scatter cursor.
__global__ __launch_bounds__(256) void alloc_kernel(const int* __restrict__ counts,
                                                    int* __restrict__ gtotal,
                                                    int* __restrict__ offs,
                                                    int* __restrict__ cursor,
                                                    float* __restrict__ dinv, int n) {
    int i = blockIdx.x * 256 + threadIdx.x;
    if (i >= n) return;
    int c = counts[i];
    int o = atomicAdd(gtotal, c);   // LLVM wave-scans this into 1 atomic per wave
    offs[i] = o;
    cursor[i] = o;
    dinv[i] = rsqrtf((float)(c + 1));
}

// ---------------- scatter edges into CSR buckets ----------------
__global__ __launch_bounds__(256) void scatter_kernel(const int* __restrict__ src,
                                                      const int* __restrict__ dst,
                                                      int* __restrict__ cursor,
                                                      const float* __restrict__ dinv,
                                                      int* __restrict__ csr_src,
                                                      float* __restrict__ csr_val, int E) {
    int e = blockIdx.x * 256 + threadIdx.x;
    if (e >= E) return;
    int d = dst[e], s = src[e];
    int j = atomicAdd(&cursor[d], 1);
    csr_src[j] = s;
    csr_val[j] = dinv[s];
}

// ---------------- T0 = x[N,128] @ w0[128,64] ----------------
// 256 threads = 4 waves; 32 rows/block (8 rows per wave), lane = output col.
__global__ __launch_bounds__(256) void mm128_kernel(const float* __restrict__ H,
                                                    const float* __restrict__ W,
                                                    float* __restrict__ T, int n) {
    __shared__ __align__(16) float wl[128 * 64];   // 32 KB
    __shared__ __align__(16) float hl[128][36];    // 32 rows + pad4 (row = 144B, 16B-aligned)
    int tid = threadIdx.x;
    int row0 = blockIdx.x * 32;
    for (int i = tid; i < 128 * 64; i += 256) wl[i] = W[i];
    // coalesced global reads: consecutive lanes -> consecutive k
    for (int i = tid; i < 32 * 128; i += 256) {
        int r = i >> 7, k = i & 127;
        int rr = row0 + r;
        hl[k][r] = (rr < n) ? H[(size_t)rr * 128 + k] : 0.f;
    }
    __syncthreads();
    int col = tid & 63;
    int w8 = (tid >> 6) * 8;  // this wave's first row within the block
    float a0=0,a1=0,a2=0,a3=0,a4=0,a5=0,a6=0,a7=0;
    #pragma unroll 4
    for (int k = 0; k < 128; ++k) {
        float wv = wl[k * 64 + col];
        float4 h4a = *reinterpret_cast<const float4*>(&hl[k][w8]);      // uniform broadcast
        float4 h4b = *reinterpret_cast<const float4*>(&hl[k][w8 + 4]);
        a0 += h4a.x * wv; a1 += h4a.y * wv; a2 += h4a.z * wv; a3 += h4a.w * wv;
        a4 += h4b.x * wv; a5 += h4b.y * wv; a6 += h4b.z * wv; a7 += h4b.w * wv;
    }
    int r0 = row0 + w8;
    float acc[8] = {a0,a1,a2,a3,a4,a5,a6,a7};
    #pragma unroll
    for (int r = 0; r < 8; ++r)
        if (r0 + r < n) T[(size_t)(r0 + r) * 64 + col] = acc[r];
}

// ---------------- fused: Tout = ELU(agg(Tin)+b) @ Wn ----------------
// Wave per node, lane = feature. Gather with 4-wide ILP. NOUT = 64.
__global__ __launch_bounds__(256) void aggmm_kernel(const float* __restrict__ T,
                                                    const int* __restrict__ offs,
                                                    const int* __restrict__ cnt,
                                                    const int* __restrict__ csr_src,
                                                    const float* __restrict__ csr_val,
                                                    const float* __restrict__ dinv,
                                                    const float* __restrict__ bias,
                                                    const float* __restrict__ Wn,
                                                    float* __restrict__ out, int n) {
    __shared__ __align__(16) float wl[64 * 64];     // 16 KB
    __shared__ __align__(16) float rowbuf[4][68];   // per-wave row scratch (272B stride)
    int tid = threadIdx.x;
    for (int i = tid; i < 64 * 64; i += 256) wl[i] = Wn[i];
    __syncthreads();
    int wv = tid >> 6, lane = tid & 63;
    int node = blockIdx.x * 4 + wv;
    if (node >= n) return;

    float di = dinv[node];
    int e0 = offs[node];
    int e1 = e0 + cnt[node];
    float a0 = 0.f, a1 = 0.f, a2 = 0.f, a3 = 0.f;
    for (int e = e0; e < e1; e += 4) {
        int c1 = (e + 1 < e1) ? e + 1 : e0;
        int c2 = (e + 2 < e1) ? e + 2 : e0;
        int c3 = (e + 3 < e1) ? e + 3 : e0;
        int s0 = csr_src[e],  s1 = csr_src[c1];
        int s2 = csr_src[c2], s3 = csr_src[c3];
        float v0 = csr_val[e];
        float v1 = (e + 1 < e1) ? csr_val[c1] : 0.f;
        float v2 = (e + 2 < e1) ? csr_val[c2] : 0.f;
        float v3 = (e + 3 < e1) ? csr_val[c3] : 0.f;
        a0 += T[(size_t)s0 * 64 + lane] * v0;
        a1 += T[(size_t)s1 * 64 + lane] * v1;
        a2 += T[(size_t)s2 * 64 + lane] * v2;
        a3 += T[(size_t)s3 * 64 + lane] * v3;
    }
    float acc = (a0 + a1) + (a2 + a3);
    acc += T[(size_t)node * 64 + lane] * di;         // self loop
    acc = acc * di + bias[lane];
    acc = acc > 0.f ? acc : expm1f(acc);             // ELU

    // next-layer matmul: o[j] = sum_k row[k] * Wn[k][j]
    rowbuf[wv][lane] = acc;
    float o = 0.f;
    #pragma unroll 8
    for (int k = 0; k < 64; k += 4) {
        float4 r4 = *reinterpret_cast<const float4*>(&rowbuf[wv][k]);  // uniform broadcast
        o += r4.x * wl[(k + 0) * 64 + lane];
        o += r4.y * wl[(k + 1) * 64 + lane];
        o += r4.z * wl[(k + 2) * 64 + lane];
        o += r4.w * wl[(k + 3) * 64 + lane];
    }
    out[(size_t)node * 64 + lane] = o;
}

// ---------------- fused final: out = softmax(ELU(agg(Tin)+b) @ fcw + fcb) ----------------
__global__ __launch_bounds__(256) void aggfc_kernel(const float* __restrict__ T,
                                                    const int* __restrict__ offs,
                                                    const int* __restrict__ cnt,
                                                    const int* __restrict__ csr_src,
                                                    const float* __restrict__ csr_val,
                                                    const float* __restrict__ dinv,
                                                    const float* __restrict__ bias,
                                                    const float* __restrict__ fcw,
                                                    const float* __restrict__ fcb,
                                                    float* __restrict__ out, int n) {
    __shared__ __align__(16) float wl[64 * 17];     // [k][j] padded stride 17
    __shared__ __align__(16) float rowbuf[4][68];
    int tid = threadIdx.x;
    for (int i = tid; i < 64 * 16; i += 256) {
        int k = i >> 4, j = i & 15;
        wl[k * 17 + j] = fcw[i];
    }
    __syncthreads();
    int wv = tid >> 6, lane = tid & 63;
    int node = blockIdx.x * 4 + wv;
    if (node >= n) return;

    float di = dinv[node];
    int e0 = offs[node];
    int e1 = e0 + cnt[node];
    float a0 = 0.f, a1 = 0.f, a2 = 0.f, a3 = 0.f;
    for (int e = e0; e < e1; e += 4) {
        int c1 = (e + 1 < e1) ? e + 1 : e0;
        int c2 = (e + 2 < e1) ? e + 2 : e0;
        int c3 = (e + 3 < e1) ? e + 3 : e0;
        int s0 = csr_src[e],  s1 = csr_src[c1];
        int s2 = csr_src[c2], s3 = csr_src[c3];
        float v0 = csr_val[e];
        float v1 = (e + 1 < e1) ? csr_val[c1] : 0.f;
        float v2 = (e + 2 < e1) ? csr_val[c2] : 0.f;
        float v3 = (e + 3 < e1) ? csr_val[c3] : 0.f;
        a0 += T[(size_t)s0 * 64 + lane] * v0;
        a1 += T[(size_t)s1 * 64 + lane] * v1;
        a2 += T[(size_t)s2 * 64 + lane] * v2;
        a3 += T[(size_t)s3 * 64 + lane] * v3;
    }
    float acc = (a0 + a1) + (a2 + a3);
    acc += T[(size_t)node * 64 + lane] * di;
    acc = acc * di + bias[lane];
    acc = acc > 0.f ? acc : expm1f(acc);

    // FC 64->16: split k over 4 lane-groups, then xor-reduce
    rowbuf[wv][lane] = acc;
    int g = lane >> 4, j = lane & 15;
    float o = 0.f;
    #pragma unroll
    for (int kk = 0; kk < 16; ++kk) {
        int k = g * 16 + kk;
        o += rowbuf[wv][k] * wl[k * 17 + j];
    }
    o += __shfl_xor(o, 16, 64);
    o += __shfl_xor(o, 32, 64);
    o += fcb[j];
    // softmax over the 16 outputs (within each 16-lane group; all groups identical)
    float m = o;
    #pragma unroll
    for (int d = 8; d; d >>= 1) m = fmaxf(m, __shfl_xor(m, d, 16));
    float ex = expf(o - m);
    float s = ex;
    #pragma unroll
    for (int d = 8; d; d >>= 1) s += __shfl_xor(s, d, 16);
    if (lane < 16) out[(size_t)node * 16 + j] = ex / s;
}

extern "C" void kernel_launch(void* const* d_in, const int* in_sizes, int n_in,
                              void* d_out, int out_size, void* d_ws, size_t ws_size,
                              hipStream_t stream) {
    const float* x   = (const float*)d_in[0];
    const int*   ei  = (const int*)d_in[1];
    const float* w0  = (const float*)d_in[2];
    const float* b0  = (const float*)d_in[3];
    const float* w1  = (const float*)d_in[4];
    const float* b1  = (const float*)d_in[5];
    const float* w2  = (const float*)d_in[6];
    const float* b2  = (const float*)d_in[7];
    const float* fcw = (const float*)d_in[8];
    const float* fcb = (const float*)d_in[9];
    float* out = (float*)d_out;

    const int N = in_sizes[0] / DIN;
    const int E = in_sizes[1] / 2;
    const int* src = ei;
    const int* dst = ei + E;

    char* p = (char*)d_ws;
    auto take = [&](size_t bytes) {
        char* q = p;
        p += (bytes + 255) & ~(size_t)255;
        return q;
    };
    int*   counts  = (int*)take((size_t)(N + 1) * 4);  // counts[N] + gtotal
    int*   gtotal  = counts + N;
    int*   offs    = (int*)take((size_t)N * 4);
    int*   cursor  = (int*)take((size_t)N * 4);
    float* dinv    = (float*)take((size_t)N * 4);
    int*   csr_src = (int*)take((size_t)E * 4);
    float* csr_val = (float*)take((size_t)E * 4);
    float* tbufA   = (float*)take((size_t)N * DH * 4);
    float* tbufB   = (float*)take((size_t)N * DH * 4);

    hipMemsetAsync(counts, 0, (size_t)(N + 1) * 4, stream);

    deg_kernel<<<(E + 255) / 256, 256, 0, stream>>>(dst, counts, E);
    alloc_kernel<<<(N + 255) / 256, 256, 0, stream>>>(counts, gtotal, offs, cursor, dinv, N);
    scatter_kernel<<<(E + 255) / 256, 256, 0, stream>>>(src, dst, cursor, dinv,
                                                        csr_src, csr_val, E);

    int node_grid = (N + 3) / 4;   // wave per node, 4 waves/block

    // T0 = x @ w0
    mm128_kernel<<<(N + 31) / 32, 256, 0, stream>>>(x, w0, tbufA, N);
    // T1 = ELU(agg(T0)+b0) @ w1
    aggmm_kernel<<<node_grid, 256, 0, stream>>>(tbufA, offs, counts, csr_src, csr_val,
                                                dinv, b0, w1, tbufB, N);
    // T2 = ELU(agg(T1)+b1) @ w2
    aggmm_kernel<<<node_grid, 256, 0, stream>>>(tbufB, offs, counts, csr_src, csr_val,
                                                dinv, b1, w2, tbufA, N);
    // out = softmax(ELU(agg(T2)+b2) @ fcw + fcb)
    aggfc_kernel<<<node_grid, 256, 0, stream>>>(tbufA, offs, counts, csr_src, csr_val,
                                                dinv, b2, fcw, fcb, out, N);
}

// Round 3
// 362.191 us; speedup vs baseline: 1.4714x; 1.0878x over previous
//
#include <hip/hip_runtime.h>
#include <hip/hip_fp16.h>
#include <math.h>

#define DIN 128
#define DH  64
#define DOUT 16

// ---------------- degree count (in-degree) ----------------
__global__ __launch_bounds__(256) void deg_kernel(const int* __restrict__ dst,
                                                  int* __restrict__ counts, int E) {
    int e = blockIdx.x * 256 + threadIdx.x;
    if (e < E) atomicAdd(&counts[dst[e]], 1);
}

// ---------------- bucket alloc: padded offs via atomic bump ----------------
__global__ __launch_bounds__(256) void alloc_kernel(const int* __restrict__ counts,
                                                    int* __restrict__ gtotal,
                                                    int* __restrict__ offs,
                                                    int* __restrict__ cursor,
                                                    float* __restrict__ dinv, int n) {
    int i = blockIdx.x * 256 + threadIdx.x;
    if (i >= n) return;
    int c = counts[i];
    int pad = (c + 7) & ~7;              // bucket padded to x8 -> branch-free 8-wide gather
    int o = atomicAdd(gtotal, pad);
    offs[i] = o;
    cursor[i] = o;
    dinv[i] = rsqrtf((float)(c + 1));
}

// ---------------- fill csr_src with dummy index n (zero row) ----------------
__global__ __launch_bounds__(256) void fill_kernel(int* __restrict__ a, int v, int cap) {
    int i = blockIdx.x * 256 + threadIdx.x;
    if (i < cap) a[i] = v;
}

// ---------------- scatter edges into CSR buckets ----------------
__global__ __launch_bounds__(256) void scatter_kernel(const int* __restrict__ src,
                                                      const int* __restrict__ dst,
                                                      int* __restrict__ cursor,
                                                      int* __restrict__ csr_src, int E) {
    int e = blockIdx.x * 256 + threadIdx.x;
    if (e >= E) return;
    int d = dst[e], s = src[e];
    int j = atomicAdd(&cursor[d], 1);
    csr_src[j] = s;
}

// ---------------- Ts0 = (x[N,128] @ w0[128,64]) * dinv[row], fp16 ----------------
__global__ __launch_bounds__(256) void mm128_kernel(const float* __restrict__ H,
                                                    const float* __restrict__ W,
                                                    const float* __restrict__ dinv,
                                                    __half* __restrict__ T, int n) {
    __shared__ __align__(16) float wl[128 * 64];   // 32 KB
    __shared__ __align__(16) float hl[128][36];    // 32 rows + pad
    int tid = threadIdx.x;
    int row0 = blockIdx.x * 32;
    for (int i = tid; i < 128 * 64; i += 256) wl[i] = W[i];
    for (int i = tid; i < 32 * 128; i += 256) {
        int r = i >> 7, k = i & 127;
        int rr = row0 + r;
        hl[k][r] = (rr < n) ? H[(size_t)rr * 128 + k] : 0.f;
    }
    if (blockIdx.x == 0 && tid < 64) T[(size_t)n * 64 + tid] = __float2half(0.f);
    __syncthreads();
    int col = tid & 63;
    int w8 = (tid >> 6) * 8;
    float a0=0,a1=0,a2=0,a3=0,a4=0,a5=0,a6=0,a7=0;
    #pragma unroll 4
    for (int k = 0; k < 128; ++k) {
        float wv = wl[k * 64 + col];
        float4 h4a = *reinterpret_cast<const float4*>(&hl[k][w8]);
        float4 h4b = *reinterpret_cast<const float4*>(&hl[k][w8 + 4]);
        a0 += h4a.x * wv; a1 += h4a.y * wv; a2 += h4a.z * wv; a3 += h4a.w * wv;
        a4 += h4b.x * wv; a5 += h4b.y * wv; a6 += h4b.z * wv; a7 += h4b.w * wv;
    }
    int r0 = row0 + w8;
    float acc[8] = {a0,a1,a2,a3,a4,a5,a6,a7};
    #pragma unroll
    for (int r = 0; r < 8; ++r)
        if (r0 + r < n) T[(size_t)(r0 + r) * 64 + col] = __float2half(acc[r] * dinv[r0 + r]);
}

// ---------------- fused: Tsout = (ELU(di*(sum Ts[src]+Ts[i]) + b) @ Wn) * di, fp16 ----------------
// Wave per node, lane = feature. 8-wide branch-free gather, W held in 64 VGPRs.
__global__ __launch_bounds__(256) void aggmm_kernel(const __half* __restrict__ T,
                                                    const int* __restrict__ offs,
                                                    const int* __restrict__ cnt,
                                                    const int* __restrict__ csr_src,
                                                    const float* __restrict__ dinv,
                                                    const float* __restrict__ bias,
                                                    const float* __restrict__ Wn,
                                                    __half* __restrict__ out, int n) {
    __shared__ __align__(16) float rowbuf[4][68];
    int tid = threadIdx.x;
    int wv = tid >> 6, lane = tid & 63;
    int node = blockIdx.x * 4 + wv;
    if (blockIdx.x == 0 && tid < 64) out[(size_t)n * 64 + tid] = __float2half(0.f);
    if (node >= n) return;

    // W column for this lane -> registers (statically indexed)
    float wreg[64];
    #pragma unroll
    for (int k = 0; k < 64; ++k) wreg[k] = Wn[k * 64 + lane];

    float di = dinv[node];
    int e0 = offs[node];
    int e1 = e0 + ((cnt[node] + 7) & ~7);
    float acc = __half2float(T[(size_t)node * 64 + lane]);  // self term Ts[i]
    float b0a = 0.f, b1a = 0.f, b2a = 0.f, b3a = 0.f;
    #pragma unroll 1
    for (int e = e0; e < e1; e += 8) {
        int4 sa = *reinterpret_cast<const int4*>(&csr_src[e]);
        int4 sb = *reinterpret_cast<const int4*>(&csr_src[e + 4]);
        float v0 = __half2float(T[(size_t)sa.x * 64 + lane]);
        float v1 = __half2float(T[(size_t)sa.y * 64 + lane]);
        float v2 = __half2float(T[(size_t)sa.z * 64 + lane]);
        float v3 = __half2float(T[(size_t)sa.w * 64 + lane]);
        float v4 = __half2float(T[(size_t)sb.x * 64 + lane]);
        float v5 = __half2float(T[(size_t)sb.y * 64 + lane]);
        float v6 = __half2float(T[(size_t)sb.z * 64 + lane]);
        float v7 = __half2float(T[(size_t)sb.w * 64 + lane]);
        b0a += v0 + v4;
        b1a += v1 + v5;
        b2a += v2 + v6;
        b3a += v3 + v7;
    }
    acc += (b0a + b1a) + (b2a + b3a);
    float h = acc * di + bias[lane];
    h = h > 0.f ? h : expm1f(h);                    // ELU

    // next-layer matmul: o[lane] = sum_k h[k] * Wn[k][lane]
    rowbuf[wv][lane] = h;                           // wave-private, no barrier needed
    float o = 0.f;
    #pragma unroll
    for (int k0 = 0; k0 < 64; k0 += 4) {
        float4 r4 = *reinterpret_cast<const float4*>(&rowbuf[wv][k0]);  // uniform broadcast
        o = fmaf(r4.x, wreg[k0 + 0], o);
        o = fmaf(r4.y, wreg[k0 + 1], o);
        o = fmaf(r4.z, wreg[k0 + 2], o);
        o = fmaf(r4.w, wreg[k0 + 3], o);
    }
    out[(size_t)node * 64 + lane] = __float2half(o * di);
}

// ---------------- fused final: out = softmax(ELU(di*(sum Ts[src]+Ts[i])+b) @ fcw + fcb) ----------------
__global__ __launch_bounds__(256) void aggfc_kernel(const __half* __restrict__ T,
                                                    const int* __restrict__ offs,
                                                    const int* __restrict__ cnt,
                                                    const int* __restrict__ csr_src,
                                                    const float* __restrict__ dinv,
                                                    const float* __restrict__ bias,
                                                    const float* __restrict__ fcw,
                                                    const float* __restrict__ fcb,
                                                    float* __restrict__ out, int n) {
    __shared__ __align__(16) float wl[64 * 17];     // [k][j] padded stride 17
    __shared__ __align__(16) float rowbuf[4][68];
    int tid = threadIdx.x;
    for (int i = tid; i < 64 * 16; i += 256) {
        int k = i >> 4, j = i & 15;
        wl[k * 17 + j] = fcw[i];
    }
    __syncthreads();
    int wv = tid >> 6, lane = tid & 63;
    int node = blockIdx.x * 4 + wv;
    if (node >= n) return;

    float di = dinv[node];
    int e0 = offs[node];
    int e1 = e0 + ((cnt[node] + 7) & ~7);
    float acc = __half2float(T[(size_t)node * 64 + lane]);
    float b0a = 0.f, b1a = 0.f, b2a = 0.f, b3a = 0.f;
    #pragma unroll 1
    for (int e = e0; e < e1; e += 8) {
        int4 sa = *reinterpret_cast<const int4*>(&csr_src[e]);
        int4 sb = *reinterpret_cast<const int4*>(&csr_src[e + 4]);
        float v0 = __half2float(T[(size_t)sa.x * 64 + lane]);
        float v1 = __half2float(T[(size_t)sa.y * 64 + lane]);
        float v2 = __half2float(T[(size_t)sa.z * 64 + lane]);
        float v3 = __half2float(T[(size_t)sa.w * 64 + lane]);
        float v4 = __half2float(T[(size_t)sb.x * 64 + lane]);
        float v5 = __half2float(T[(size_t)sb.y * 64 + lane]);
        float v6 = __half2float(T[(size_t)sb.z * 64 + lane]);
        float v7 = __half2float(T[(size_t)sb.w * 64 + lane]);
        b0a += v0 + v4;
        b1a += v1 + v5;
        b2a += v2 + v6;
        b3a += v3 + v7;
    }
    acc += (b0a + b1a) + (b2a + b3a);
    float h = acc * di + bias[lane];
    h = h > 0.f ? h : expm1f(h);

    // FC 64->16: split k over 4 lane-groups, then xor-reduce
    rowbuf[wv][lane] = h;
    int g = lane >> 4, j = lane & 15;
    float o = 0.f;
    #pragma unroll
    for (int kk = 0; kk < 16; ++kk) {
        int k = g * 16 + kk;
        o += rowbuf[wv][k] * wl[k * 17 + j];
    }
    o += __shfl_xor(o, 16, 64);
    o += __shfl_xor(o, 32, 64);
    o += fcb[j];
    float m = o;
    #pragma unroll
    for (int d = 8; d; d >>= 1) m = fmaxf(m, __shfl_xor(m, d, 16));
    float ex = expf(o - m);
    float s = ex;
    #pragma unroll
    for (int d = 8; d; d >>= 1) s += __shfl_xor(s, d, 16);
    if (lane < 16) out[(size_t)node * 16 + j] = ex / s;
}

extern "C" void kernel_launch(void* const* d_in, const int* in_sizes, int n_in,
                              void* d_out, int out_size, void* d_ws, size_t ws_size,
                              hipStream_t stream) {
    const float* x   = (const float*)d_in[0];
    const int*   ei  = (const int*)d_in[1];
    const float* w0  = (const float*)d_in[2];
    const float* b0  = (const float*)d_in[3];
    const float* w1  = (const float*)d_in[4];
    const float* b1  = (const float*)d_in[5];
    const float* w2  = (const float*)d_in[6];
    const float* b2  = (const float*)d_in[7];
    const float* fcw = (const float*)d_in[8];
    const float* fcb = (const float*)d_in[9];
    float* out = (float*)d_out;

    const int N = in_sizes[0] / DIN;
    const int E = in_sizes[1] / 2;
    const int* src = ei;
    const int* dst = ei + E;
    const int csr_cap = E + 8 * N + 8;

    char* p = (char*)d_ws;
    auto take = [&](size_t bytes) {
        char* q = p;
        p += (bytes + 255) & ~(size_t)255;
        return q;
    };
    int*    counts  = (int*)take((size_t)(N + 1) * 4);  // counts[N] = gtotal
    int*    gtotal  = counts + N;
    int*    offs    = (int*)take((size_t)N * 4);
    int*    cursor  = (int*)take((size_t)N * 4);
    float*  dinv    = (float*)take((size_t)N * 4);
    int*    csr_src = (int*)take((size_t)csr_cap * 4);
    __half* tbufA   = (__half*)take((size_t)(N + 1) * DH * 2);
    __half* tbufB   = (__half*)take((size_t)(N + 1) * DH * 2);

    hipMemsetAsync(counts, 0, (size_t)(N + 1) * 4, stream);

    deg_kernel<<<(E + 255) / 256, 256, 0, stream>>>(dst, counts, E);
    alloc_kernel<<<(N + 255) / 256, 256, 0, stream>>>(counts, gtotal, offs, cursor, dinv, N);
    fill_kernel<<<(csr_cap + 255) / 256, 256, 0, stream>>>(csr_src, N, csr_cap);
    scatter_kernel<<<(E + 255) / 256, 256, 0, stream>>>(src, dst, cursor, csr_src, E);

    int node_grid = (N + 3) / 4;

    mm128_kernel<<<(N + 31) / 32, 256, 0, stream>>>(x, w0, dinv, tbufA, N);
    aggmm_kernel<<<node_grid, 256, 0, stream>>>(tbufA, offs, counts, csr_src,
                                                dinv, b0, w1, tbufB, N);
    aggmm_kernel<<<node_grid, 256, 0, stream>>>(tbufB, offs, counts, csr_src,
                                                dinv, b1, w2, tbufA, N);
    aggfc_kernel<<<node_grid, 256, 0, stream>>>(tbufA, offs, counts, csr_src,
                                                dinv, b2, fcw, fcb, out, N);
}

// Round 4
// 300.956 us; speedup vs baseline: 1.7708x; 1.2035x over previous
//
#include <hip/hip_runtime.h>
#include <hip/hip_fp16.h>
#include <math.h>

#define DIN 128
#define DH  64
#define DOUT 16
#define NWIN 8

// ---------------- degree count (in-degree) ----------------
__global__ __launch_bounds__(256) void deg_kernel(const int* __restrict__ dst,
                                                  int* __restrict__ counts, int E) {
    int e = blockIdx.x * 256 + threadIdx.x;
    if (e < E) atomicAdd(&counts[dst[e]], 1);
}

// ---------------- bucket alloc: padded offs via atomic bump ----------------
__global__ __launch_bounds__(256) void alloc_kernel(const int* __restrict__ counts,
                                                    int* __restrict__ gtotal,
                                                    int* __restrict__ offs,
                                                    int* __restrict__ cursor,
                                                    float* __restrict__ dinv, int n) {
    int i = blockIdx.x * 256 + threadIdx.x;
    if (i >= n) return;
    int c = counts[i];
    int pad = (c + 7) & ~7;              // bucket padded to x8 -> branch-free 8-wide gather
    int o = atomicAdd(gtotal, pad);
    offs[i] = o;
    cursor[i] = o;
    dinv[i] = rsqrtf((float)(c + 1));
}

// ---------------- fill csr_src with dummy index n (zero row) ----------------
__global__ __launch_bounds__(256) void fill_kernel(int* __restrict__ a, int v, int cap) {
    int i = blockIdx.x * 256 + threadIdx.x;
    if (i < cap) a[i] = v;
}

// ---------------- XCD-windowed scatter: window = blockIdx & 7 ----------------
// All blocks with the same (blockIdx&7) land on the same XCD (round-robin
// dispatch heuristic) and exclusively own one dst-range window, so csr_src
// lines are filled completely within one L2 before writeback.
__global__ __launch_bounds__(256) void scatter_kernel(const int* __restrict__ src,
                                                      const int* __restrict__ dst,
                                                      int* __restrict__ cursor,
                                                      int* __restrict__ csr_src,
                                                      int E, int winSize) {
    int win = blockIdx.x & (NWIN - 1);
    int group = blockIdx.x >> 3;
    int nGroups = gridDim.x >> 3;
    int lo = win * winSize, hi = lo + winSize;
    int stride = nGroups * 256;
    for (int e = group * 256 + threadIdx.x; e < E; e += stride) {
        int d = dst[e];
        if (d >= lo && d < hi) {
            int j = atomicAdd(&cursor[d], 1);
            csr_src[j] = src[e];
        }
    }
}

// ---------------- Ts0 = (x[N,128] @ w0[128,64]) * dinv[row], fp16 ----------------
__global__ __launch_bounds__(256) void mm128_kernel(const float* __restrict__ H,
                                                    const float* __restrict__ W,
                                                    const float* __restrict__ dinv,
                                                    __half* __restrict__ T, int n) {
    __shared__ __align__(16) float wl[128 * 64];   // 32 KB
    __shared__ __align__(16) float hl[128][36];    // 32 rows + pad
    int tid = threadIdx.x;
    int row0 = blockIdx.x * 32;
    for (int i = tid; i < 128 * 64; i += 256) wl[i] = W[i];
    for (int i = tid; i < 32 * 128; i += 256) {
        int r = i >> 7, k = i & 127;
        int rr = row0 + r;
        hl[k][r] = (rr < n) ? H[(size_t)rr * 128 + k] : 0.f;
    }
    if (blockIdx.x == 0 && tid < 64) T[(size_t)n * 64 + tid] = __float2half(0.f);
    __syncthreads();
    int col = tid & 63;
    int w8 = (tid >> 6) * 8;
    float a0=0,a1=0,a2=0,a3=0,a4=0,a5=0,a6=0,a7=0;
    #pragma unroll 4
    for (int k = 0; k < 128; ++k) {
        float wv = wl[k * 64 + col];
        float4 h4a = *reinterpret_cast<const float4*>(&hl[k][w8]);
        float4 h4b = *reinterpret_cast<const float4*>(&hl[k][w8 + 4]);
        a0 += h4a.x * wv; a1 += h4a.y * wv; a2 += h4a.z * wv; a3 += h4a.w * wv;
        a4 += h4b.x * wv; a5 += h4b.y * wv; a6 += h4b.z * wv; a7 += h4b.w * wv;
    }
    int r0 = row0 + w8;
    float acc[8] = {a0,a1,a2,a3,a4,a5,a6,a7};
    #pragma unroll
    for (int r = 0; r < 8; ++r)
        if (r0 + r < n) T[(size_t)(r0 + r) * 64 + col] = __float2half(acc[r] * dinv[r0 + r]);
}

// ---------------- fused: Tsout = (ELU(di*(sum Ts[src]+Ts[i]) + b) @ Wn) * di ----------------
// HALF-WAVE per node: 32 lanes x half2 (2 features/lane). 8 rows in flight
// per half-wave, W staged in LDS (low VGPR -> full occupancy).
__global__ __launch_bounds__(256) void aggmm_kernel(const __half* __restrict__ T,
                                                    const int* __restrict__ offs,
                                                    const int* __restrict__ cnt,
                                                    const int* __restrict__ csr_src,
                                                    const float* __restrict__ dinv,
                                                    const float* __restrict__ bias,
                                                    const float* __restrict__ Wn,
                                                    __half* __restrict__ out, int n) {
    __shared__ __align__(16) float wl[64 * 64];     // 16 KB
    __shared__ __align__(16) float rowbuf[8][68];   // per-half-wave row (272B stride)
    int tid = threadIdx.x;
    for (int i = tid; i < 64 * 64; i += 256) wl[i] = Wn[i];
    if (blockIdx.x == 0 && tid < 64) out[(size_t)n * 64 + tid] = __float2half(0.f);
    __syncthreads();
    int hw = tid >> 5;       // half-wave id within block: 0..7
    int f2 = tid & 31;       // feature-pair index
    int node = blockIdx.x * 8 + hw;
    if (node >= n) return;

    const __half2* T2 = reinterpret_cast<const __half2*>(T);
    float di = dinv[node];
    int e0 = offs[node];
    int e1 = e0 + ((cnt[node] + 7) & ~7);
    float2 sv = __half22float2(T2[(size_t)node * 32 + f2]);   // self term
    float ax0 = sv.x, ay0 = sv.y;
    float ax1=0, ay1=0, ax2=0, ay2=0, ax3=0, ay3=0;
    #pragma unroll 1
    for (int e = e0; e < e1; e += 8) {
        int4 sa = *reinterpret_cast<const int4*>(&csr_src[e]);
        int4 sb = *reinterpret_cast<const int4*>(&csr_src[e + 4]);
        float2 v0 = __half22float2(T2[(size_t)sa.x * 32 + f2]);
        float2 v1 = __half22float2(T2[(size_t)sa.y * 32 + f2]);
        float2 v2 = __half22float2(T2[(size_t)sa.z * 32 + f2]);
        float2 v3 = __half22float2(T2[(size_t)sa.w * 32 + f2]);
        float2 v4 = __half22float2(T2[(size_t)sb.x * 32 + f2]);
        float2 v5 = __half22float2(T2[(size_t)sb.y * 32 + f2]);
        float2 v6 = __half22float2(T2[(size_t)sb.z * 32 + f2]);
        float2 v7 = __half22float2(T2[(size_t)sb.w * 32 + f2]);
        ax0 += v0.x + v4.x;  ay0 += v0.y + v4.y;
        ax1 += v1.x + v5.x;  ay1 += v1.y + v5.y;
        ax2 += v2.x + v6.x;  ay2 += v2.y + v6.y;
        ax3 += v3.x + v7.x;  ay3 += v3.y + v7.y;
    }
    float hx = (ax0 + ax1) + (ax2 + ax3);
    float hy = (ay0 + ay1) + (ay2 + ay3);
    float2 bv = *reinterpret_cast<const float2*>(&bias[2 * f2]);
    hx = hx * di + bv.x;
    hy = hy * di + bv.y;
    hx = hx > 0.f ? hx : expm1f(hx);                // ELU
    hy = hy > 0.f ? hy : expm1f(hy);

    // next-layer matmul: lane produces outputs j=2*f2, 2*f2+1
    *reinterpret_cast<float2*>(&rowbuf[hw][2 * f2]) = make_float2(hx, hy);
    float ox = 0.f, oy = 0.f;
    #pragma unroll
    for (int k0 = 0; k0 < 64; k0 += 4) {
        float4 r4 = *reinterpret_cast<const float4*>(&rowbuf[hw][k0]);  // broadcast
        float2 w0 = *reinterpret_cast<const float2*>(&wl[(k0 + 0) * 64 + 2 * f2]);
        float2 w1 = *reinterpret_cast<const float2*>(&wl[(k0 + 1) * 64 + 2 * f2]);
        float2 w2 = *reinterpret_cast<const float2*>(&wl[(k0 + 2) * 64 + 2 * f2]);
        float2 w3 = *reinterpret_cast<const float2*>(&wl[(k0 + 3) * 64 + 2 * f2]);
        ox = fmaf(r4.x, w0.x, ox); oy = fmaf(r4.x, w0.y, oy);
        ox = fmaf(r4.y, w1.x, ox); oy = fmaf(r4.y, w1.y, oy);
        ox = fmaf(r4.z, w2.x, ox); oy = fmaf(r4.z, w2.y, oy);
        ox = fmaf(r4.w, w3.x, ox); oy = fmaf(r4.w, w3.y, oy);
    }
    __half2* out2 = reinterpret_cast<__half2*>(out);
    out2[(size_t)node * 32 + f2] = __float22half2_rn(make_float2(ox * di, oy * di));
}

// ---------------- fused final: out = softmax(ELU(di*(sum Ts[src]+Ts[i])+b) @ fcw + fcb) ----------------
__global__ __launch_bounds__(256) void aggfc_kernel(const __half* __restrict__ T,
                                                    const int* __restrict__ offs,
                                                    const int* __restrict__ cnt,
                                                    const int* __restrict__ csr_src,
                                                    const float* __restrict__ dinv,
                                                    const float* __restrict__ bias,
                                                    const float* __restrict__ fcw,
                                                    const float* __restrict__ fcb,
                                                    float* __restrict__ out, int n) {
    __shared__ __align__(16) float wl[64 * 17];     // [k][j] stride 17
    __shared__ __align__(16) float rowbuf[8][68];
    int tid = threadIdx.x;
    for (int i = tid; i < 64 * 16; i += 256) {
        int k = i >> 4, j = i & 15;
        wl[k * 17 + j] = fcw[i];
    }
    __syncthreads();
    int hw = tid >> 5, f2 = tid & 31;
    int node = blockIdx.x * 8 + hw;
    if (node >= n) return;

    const __half2* T2 = reinterpret_cast<const __half2*>(T);
    float di = dinv[node];
    int e0 = offs[node];
    int e1 = e0 + ((cnt[node] + 7) & ~7);
    float2 sv = __half22float2(T2[(size_t)node * 32 + f2]);
    float ax0 = sv.x, ay0 = sv.y;
    float ax1=0, ay1=0, ax2=0, ay2=0, ax3=0, ay3=0;
    #pragma unroll 1
    for (int e = e0; e < e1; e += 8) {
        int4 sa = *reinterpret_cast<const int4*>(&csr_src[e]);
        int4 sb = *reinterpret_cast<const int4*>(&csr_src[e + 4]);
        float2 v0 = __half22float2(T2[(size_t)sa.x * 32 + f2]);
        float2 v1 = __half22float2(T2[(size_t)sa.y * 32 + f2]);
        float2 v2 = __half22float2(T2[(size_t)sa.z * 32 + f2]);
        float2 v3 = __half22float2(T2[(size_t)sa.w * 32 + f2]);
        float2 v4 = __half22float2(T2[(size_t)sb.x * 32 + f2]);
        float2 v5 = __half22float2(T2[(size_t)sb.y * 32 + f2]);
        float2 v6 = __half22float2(T2[(size_t)sb.z * 32 + f2]);
        float2 v7 = __half22float2(T2[(size_t)sb.w * 32 + f2]);
        ax0 += v0.x + v4.x;  ay0 += v0.y + v4.y;
        ax1 += v1.x + v5.x;  ay1 += v1.y + v5.y;
        ax2 += v2.x + v6.x;  ay2 += v2.y + v6.y;
        ax3 += v3.x + v7.x;  ay3 += v3.y + v7.y;
    }
    float hx = (ax0 + ax1) + (ax2 + ax3);
    float hy = (ay0 + ay1) + (ay2 + ay3);
    float2 bv = *reinterpret_cast<const float2*>(&bias[2 * f2]);
    hx = hx * di + bv.x;
    hy = hy * di + bv.y;
    hx = hx > 0.f ? hx : expm1f(hx);
    hy = hy > 0.f ? hy : expm1f(hy);
    *reinterpret_cast<float2*>(&rowbuf[hw][2 * f2]) = make_float2(hx, hy);

    // FC 64->16: k split over 2 groups of 16 lanes per half-wave
    int g = f2 >> 4;          // k-half
    int j = f2 & 15;          // output index
    float o = 0.f;
    #pragma unroll
    for (int kk = 0; kk < 32; ++kk) {
        int k = g * 32 + kk;
        o += rowbuf[hw][k] * wl[k * 17 + j];
    }
    o += __shfl_xor(o, 16, 64);   // combine the two k-halves
    o += fcb[j];
    float m = o;
    #pragma unroll
    for (int d = 8; d; d >>= 1) m = fmaxf(m, __shfl_xor(m, d, 64));
    float ex = expf(o - m);
    float s = ex;
    #pragma unroll
    for (int d = 8; d; d >>= 1) s += __shfl_xor(s, d, 64);
    if ((f2 & 16) == 0) out[(size_t)node * 16 + j] = ex / s;
}

extern "C" void kernel_launch(void* const* d_in, const int* in_sizes, int n_in,
                              void* d_out, int out_size, void* d_ws, size_t ws_size,
                              hipStream_t stream) {
    const float* x   = (const float*)d_in[0];
    const int*   ei  = (const int*)d_in[1];
    const float* w0  = (const float*)d_in[2];
    const float* b0  = (const float*)d_in[3];
    const float* w1  = (const float*)d_in[4];
    const float* b1  = (const float*)d_in[5];
    const float* w2  = (const float*)d_in[6];
    const float* b2  = (const float*)d_in[7];
    const float* fcw = (const float*)d_in[8];
    const float* fcb = (const float*)d_in[9];
    float* out = (float*)d_out;

    const int N = in_sizes[0] / DIN;
    const int E = in_sizes[1] / 2;
    const int* src = ei;
    const int* dst = ei + E;
    const int csr_cap = E + 8 * N + 8;

    char* p = (char*)d_ws;
    auto take = [&](size_t bytes) {
        char* q = p;
        p += (bytes + 255) & ~(size_t)255;
        return q;
    };
    int*    counts  = (int*)take((size_t)(N + 1) * 4);  // counts[N] = gtotal
    int*    gtotal  = counts + N;
    int*    offs    = (int*)take((size_t)N * 4);
    int*    cursor  = (int*)take((size_t)N * 4);
    float*  dinv    = (float*)take((size_t)N * 4);
    int*    csr_src = (int*)take((size_t)csr_cap * 4);
    __half* tbufA   = (__half*)take((size_t)(N + 1) * DH * 2);
    __half* tbufB   = (__half*)take((size_t)(N + 1) * DH * 2);

    hipMemsetAsync(counts, 0, (size_t)(N + 1) * 4, stream);

    deg_kernel<<<(E + 255) / 256, 256, 0, stream>>>(dst, counts, E);
    alloc_kernel<<<(N + 255) / 256, 256, 0, stream>>>(counts, gtotal, offs, cursor, dinv, N);
    fill_kernel<<<(csr_cap + 255) / 256, 256, 0, stream>>>(csr_src, N, csr_cap);
    int winSize = (N + NWIN - 1) / NWIN;
    scatter_kernel<<<1024, 256, 0, stream>>>(src, dst, cursor, csr_src, E, winSize);

    int node_grid = (N + 7) / 8;   // half-wave per node, 8 nodes/block

    mm128_kernel<<<(N + 31) / 32, 256, 0, stream>>>(x, w0, dinv, tbufA, N);
    aggmm_kernel<<<node_grid, 256, 0, stream>>>(tbufA, offs, counts, csr_src,
                                                dinv, b0, w1, tbufB, N);
    aggmm_kernel<<<node_grid, 256, 0, stream>>>(tbufB, offs, counts, csr_src,
                                                dinv, b1, w2, tbufA, N);
    aggfc_kernel<<<node_grid, 256, 0, stream>>>(tbufA, offs, counts, csr_src,
                                                dinv, b2, fcw, fcb, out, N);
}

// Round 5
// 278.214 us; speedup vs baseline: 1.9155x; 1.0817x over previous
//
#include <hip/hip_runtime.h>
#include <hip/hip_fp16.h>
#include <math.h>

#define DIN 128
#define DH  64
#define DOUT 16
#define NWIN 8

typedef _Float16 f16x8 __attribute__((ext_vector_type(8)));
typedef float f32x4 __attribute__((ext_vector_type(4)));

// ---------------- degree count (in-degree) ----------------
__global__ __launch_bounds__(256) void deg_kernel(const int* __restrict__ dst,
                                                  int* __restrict__ counts, int E) {
    int e = blockIdx.x * 256 + threadIdx.x;
    if (e < E) atomicAdd(&counts[dst[e]], 1);
}

// ---------------- bucket alloc: padded offs via atomic bump ----------------
__global__ __launch_bounds__(256) void alloc_kernel(const int* __restrict__ counts,
                                                    int* __restrict__ gtotal,
                                                    int* __restrict__ offs,
                                                    int* __restrict__ cursor,
                                                    float* __restrict__ dinv, int n) {
    int i = blockIdx.x * 256 + threadIdx.x;
    if (i >= n) return;
    int c = counts[i];
    int pad = (c + 7) & ~7;              // bucket padded to x8 -> branch-free 8-wide gather
    int o = atomicAdd(gtotal, pad);
    offs[i] = o;
    cursor[i] = o;
    dinv[i] = rsqrtf((float)(c + 1));
}

// ---------------- fill csr_src with dummy index n (zero row) ----------------
__global__ __launch_bounds__(256) void fill_kernel(int* __restrict__ a, int v, int cap) {
    int i = blockIdx.x * 256 + threadIdx.x;
    if (i < cap) a[i] = v;
}

// ---------------- XCD-windowed scatter: window = blockIdx & 7 ----------------
__global__ __launch_bounds__(256) void scatter_kernel(const int* __restrict__ src,
                                                      const int* __restrict__ dst,
                                                      int* __restrict__ cursor,
                                                      int* __restrict__ csr_src,
                                                      int E, int winSize) {
    int win = blockIdx.x & (NWIN - 1);
    int group = blockIdx.x >> 3;
    int nGroups = gridDim.x >> 3;
    int lo = win * winSize, hi = lo + winSize;
    int stride = nGroups * 256;
    for (int e = group * 256 + threadIdx.x; e < E; e += stride) {
        int d = dst[e];
        if (d >= lo && d < hi) {
            int j = atomicAdd(&cursor[d], 1);
            csr_src[j] = src[e];
        }
    }
}

// ---------------- Ts0 = (x[N,128] @ w0[128,64]) * dinv[row], fp16, via MFMA ----------------
// Split-fp16 (hi/lo) 3-term MFMA: acc = Ah*Bh + Al*Bh + Ah*Bl -> fp32-level accuracy.
// One wave = one 16-row tile x all 64 cols. A frags fed directly from coalesced
// float4 loads of x (cvt+split in-register). B frags staged once per block into
// frag layout; lane reads contiguous 16B -> conflict-free ds_read_b128.
__global__ __launch_bounds__(256) void mm128_mfma(const float* __restrict__ H,
                                                  const float* __restrict__ W,
                                                  const float* __restrict__ dinv,
                                                  __half* __restrict__ T, int n, int nTiles) {
    __shared__ _Float16 bhi[4][4][64][8];   // [kt][ct][lane][j], 8 KB
    __shared__ _Float16 blo[4][4][64][8];
    int tid = threadIdx.x;
    // stage W frags: coalesced global read, scatter to frag layout
    for (int it = 0; it < 32; ++it) {
        int idx = it * 256 + tid;           // 8192 = 128 k * 64 n
        int k = idx >> 6, nn = idx & 63;
        float w = W[idx];
        _Float16 h = (_Float16)w;
        _Float16 l = (_Float16)(w - (float)h);
        int kt = k >> 5, kr = k & 31;
        int g = kr >> 3, j = kr & 7;
        int ct = nn >> 4, c = nn & 15;
        int ln = g * 16 + c;
        bhi[kt][ct][ln][j] = h;
        blo[kt][ct][ln][j] = l;
    }
    if (blockIdx.x == 0 && tid < 64) T[(size_t)n * 64 + tid] = __float2half(0.f);
    __syncthreads();

    int wave = blockIdx.x * 4 + (tid >> 6);
    if (wave >= nTiles) return;
    int lane = tid & 63;
    f16x8 Bh[4][4], Bl[4][4];
    #pragma unroll
    for (int kt = 0; kt < 4; ++kt)
        #pragma unroll
        for (int ct = 0; ct < 4; ++ct) {
            Bh[kt][ct] = *(const f16x8*)&bhi[kt][ct][lane][0];
            Bl[kt][ct] = *(const f16x8*)&blo[kt][ct][lane][0];
        }
    int row0 = wave * 16;
    int arow = row0 + (lane & 15);
    if (arow >= n) arow = n - 1;            // clamp for tail tile
    const float* hp = H + (size_t)arow * 128 + ((lane >> 4) << 3);
    f32x4 acc[4];
    #pragma unroll
    for (int ct = 0; ct < 4; ++ct) acc[ct] = (f32x4){0.f, 0.f, 0.f, 0.f};
    #pragma unroll
    for (int kt = 0; kt < 4; ++kt) {
        float4 p0 = *(const float4*)(hp + kt * 32);
        float4 p1 = *(const float4*)(hp + kt * 32 + 4);
        float v[8] = {p0.x, p0.y, p0.z, p0.w, p1.x, p1.y, p1.z, p1.w};
        f16x8 ah, al;
        #pragma unroll
        for (int j = 0; j < 8; ++j) {
            _Float16 h = (_Float16)v[j];
            ah[j] = h;
            al[j] = (_Float16)(v[j] - (float)h);
        }
        #pragma unroll
        for (int ct = 0; ct < 4; ++ct) {
            acc[ct] = __builtin_amdgcn_mfma_f32_16x16x32_f16(ah, Bh[kt][ct], acc[ct], 0, 0, 0);
            acc[ct] = __builtin_amdgcn_mfma_f32_16x16x32_f16(al, Bh[kt][ct], acc[ct], 0, 0, 0);
            acc[ct] = __builtin_amdgcn_mfma_f32_16x16x32_f16(ah, Bl[kt][ct], acc[ct], 0, 0, 0);
        }
    }
    // C/D layout: col = lane&15 (+16*ct), row = row0 + (lane>>4)*4 + r   [m89]
    int rbase = row0 + ((lane >> 4) << 2);
    int cbase = lane & 15;
    #pragma unroll
    for (int r = 0; r < 4; ++r) {
        int row = rbase + r;
        if (row < n) {
            float d = dinv[row];
            #pragma unroll
            for (int ct = 0; ct < 4; ++ct)
                T[(size_t)row * 64 + ct * 16 + cbase] = __float2half(acc[ct][r] * d);
        }
    }
}

// ---------------- fused: Tsout = (ELU(di*(sum Ts[src]+Ts[i]) + b) @ Wn) * di ----------------
// HALF-WAVE per node: 32 lanes x half2 (2 features/lane). 8 rows in flight
// per half-wave, W staged in LDS (low VGPR -> full occupancy).
__global__ __launch_bounds__(256) void aggmm_kernel(const __half* __restrict__ T,
                                                    const int* __restrict__ offs,
                                                    const int* __restrict__ cnt,
                                                    const int* __restrict__ csr_src,
                                                    const float* __restrict__ dinv,
                                                    const float* __restrict__ bias,
                                                    const float* __restrict__ Wn,
                                                    __half* __restrict__ out, int n) {
    __shared__ __align__(16) float wl[64 * 64];     // 16 KB
    __shared__ __align__(16) float rowbuf[8][68];   // per-half-wave row (272B stride)
    int tid = threadIdx.x;
    for (int i = tid; i < 64 * 64; i += 256) wl[i] = Wn[i];
    if (blockIdx.x == 0 && tid < 64) out[(size_t)n * 64 + tid] = __float2half(0.f);
    __syncthreads();
    int hw = tid >> 5;       // half-wave id within block: 0..7
    int f2 = tid & 31;       // feature-pair index
    int node = blockIdx.x * 8 + hw;
    if (node >= n) return;

    const __half2* T2 = reinterpret_cast<const __half2*>(T);
    float di = dinv[node];
    int e0 = offs[node];
    int e1 = e0 + ((cnt[node] + 7) & ~7);
    float2 sv = __half22float2(T2[(size_t)node * 32 + f2]);   // self term
    float ax0 = sv.x, ay0 = sv.y;
    float ax1=0, ay1=0, ax2=0, ay2=0, ax3=0, ay3=0;
    #pragma unroll 1
    for (int e = e0; e < e1; e += 8) {
        int4 sa = *reinterpret_cast<const int4*>(&csr_src[e]);
        int4 sb = *reinterpret_cast<const int4*>(&csr_src[e + 4]);
        float2 v0 = __half22float2(T2[(size_t)sa.x * 32 + f2]);
        float2 v1 = __half22float2(T2[(size_t)sa.y * 32 + f2]);
        float2 v2 = __half22float2(T2[(size_t)sa.z * 32 + f2]);
        float2 v3 = __half22float2(T2[(size_t)sa.w * 32 + f2]);
        float2 v4 = __half22float2(T2[(size_t)sb.x * 32 + f2]);
        float2 v5 = __half22float2(T2[(size_t)sb.y * 32 + f2]);
        float2 v6 = __half22float2(T2[(size_t)sb.z * 32 + f2]);
        float2 v7 = __half22float2(T2[(size_t)sb.w * 32 + f2]);
        ax0 += v0.x + v4.x;  ay0 += v0.y + v4.y;
        ax1 += v1.x + v5.x;  ay1 += v1.y + v5.y;
        ax2 += v2.x + v6.x;  ay2 += v2.y + v6.y;
        ax3 += v3.x + v7.x;  ay3 += v3.y + v7.y;
    }
    float hx = (ax0 + ax1) + (ax2 + ax3);
    float hy = (ay0 + ay1) + (ay2 + ay3);
    float2 bv = *reinterpret_cast<const float2*>(&bias[2 * f2]);
    hx = hx * di + bv.x;
    hy = hy * di + bv.y;
    hx = hx > 0.f ? hx : expm1f(hx);                // ELU
    hy = hy > 0.f ? hy : expm1f(hy);

    // next-layer matmul: lane produces outputs j=2*f2, 2*f2+1
    *reinterpret_cast<float2*>(&rowbuf[hw][2 * f2]) = make_float2(hx, hy);
    float ox = 0.f, oy = 0.f;
    #pragma unroll
    for (int k0 = 0; k0 < 64; k0 += 4) {
        float4 r4 = *reinterpret_cast<const float4*>(&rowbuf[hw][k0]);  // broadcast
        float2 w0 = *reinterpret_cast<const float2*>(&wl[(k0 + 0) * 64 + 2 * f2]);
        float2 w1 = *reinterpret_cast<const float2*>(&wl[(k0 + 1) * 64 + 2 * f2]);
        float2 w2 = *reinterpret_cast<const float2*>(&wl[(k0 + 2) * 64 + 2 * f2]);
        float2 w3 = *reinterpret_cast<const float2*>(&wl[(k0 + 3) * 64 + 2 * f2]);
        ox = fmaf(r4.x, w0.x, ox); oy = fmaf(r4.x, w0.y, oy);
        ox = fmaf(r4.y, w1.x, ox); oy = fmaf(r4.y, w1.y, oy);
        ox = fmaf(r4.z, w2.x, ox); oy = fmaf(r4.z, w2.y, oy);
        ox = fmaf(r4.w, w3.x, ox); oy = fmaf(r4.w, w3.y, oy);
    }
    __half2* out2 = reinterpret_cast<__half2*>(out);
    out2[(size_t)node * 32 + f2] = __float22half2_rn(make_float2(ox * di, oy * di));
}

// ---------------- fused final: out = softmax(ELU(di*(sum Ts[src]+Ts[i])+b) @ fcw + fcb) ----------------
__global__ __launch_bounds__(256) void aggfc_kernel(const __half* __restrict__ T,
                                                    const int* __restrict__ offs,
                                                    const int* __restrict__ cnt,
                                                    const int* __restrict__ csr_src,
                                                    const float* __restrict__ dinv,
                                                    const float* __restrict__ bias,
                                                    const float* __restrict__ fcw,
                                                    const float* __restrict__ fcb,
                                                    float* __restrict__ out, int n) {
    __shared__ __align__(16) float wl[64 * 17];     // [k][j] stride 17
    __shared__ __align__(16) float rowbuf[8][68];
    int tid = threadIdx.x;
    for (int i = tid; i < 64 * 16; i += 256) {
        int k = i >> 4, j = i & 15;
        wl[k * 17 + j] = fcw[i];
    }
    __syncthreads();
    int hw = tid >> 5, f2 = tid & 31;
    int node = blockIdx.x * 8 + hw;
    if (node >= n) return;

    const __half2* T2 = reinterpret_cast<const __half2*>(T);
    float di = dinv[node];
    int e0 = offs[node];
    int e1 = e0 + ((cnt[node] + 7) & ~7);
    float2 sv = __half22float2(T2[(size_t)node * 32 + f2]);
    float ax0 = sv.x, ay0 = sv.y;
    float ax1=0, ay1=0, ax2=0, ay2=0, ax3=0, ay3=0;
    #pragma unroll 1
    for (int e = e0; e < e1; e += 8) {
        int4 sa = *reinterpret_cast<const int4*>(&csr_src[e]);
        int4 sb = *reinterpret_cast<const int4*>(&csr_src[e + 4]);
        float2 v0 = __half22float2(T2[(size_t)sa.x * 32 + f2]);
        float2 v1 = __half22float2(T2[(size_t)sa.y * 32 + f2]);
        float2 v2 = __half22float2(T2[(size_t)sa.z * 32 + f2]);
        float2 v3 = __half22float2(T2[(size_t)sa.w * 32 + f2]);
        float2 v4 = __half22float2(T2[(size_t)sb.x * 32 + f2]);
        float2 v5 = __half22float2(T2[(size_t)sb.y * 32 + f2]);
        float2 v6 = __half22float2(T2[(size_t)sb.z * 32 + f2]);
        float2 v7 = __half22float2(T2[(size_t)sb.w * 32 + f2]);
        ax0 += v0.x + v4.x;  ay0 += v0.y + v4.y;
        ax1 += v1.x + v5.x;  ay1 += v1.y + v5.y;
        ax2 += v2.x + v6.x;  ay2 += v2.y + v6.y;
        ax3 += v3.x + v7.x;  ay3 += v3.y + v7.y;
    }
    float hx = (ax0 + ax1) + (ax2 + ax3);
    float hy = (ay0 + ay1) + (ay2 + ay3);
    float2 bv = *reinterpret_cast<const float2*>(&bias[2 * f2]);
    hx = hx * di + bv.x;
    hy = hy * di + bv.y;
    hx = hx > 0.f ? hx : expm1f(hx);
    hy = hy > 0.f ? hy : expm1f(hy);
    *reinterpret_cast<float2*>(&rowbuf[hw][2 * f2]) = make_float2(hx, hy);

    // FC 64->16: k split over 2 groups of 16 lanes per half-wave
    int g = f2 >> 4;          // k-half
    int j = f2 & 15;          // output index
    float o = 0.f;
    #pragma unroll
    for (int kk = 0; kk < 32; ++kk) {
        int k = g * 32 + kk;
        o += rowbuf[hw][k] * wl[k * 17 + j];
    }
    o += __shfl_xor(o, 16, 64);   // combine the two k-halves
    o += fcb[j];
    float m = o;
    #pragma unroll
    for (int d = 8; d; d >>= 1) m = fmaxf(m, __shfl_xor(m, d, 64));
    float ex = expf(o - m);
    float s = ex;
    #pragma unroll
    for (int d = 8; d; d >>= 1) s += __shfl_xor(s, d, 64);
    if ((f2 & 16) == 0) out[(size_t)node * 16 + j] = ex / s;
}

extern "C" void kernel_launch(void* const* d_in, const int* in_sizes, int n_in,
                              void* d_out, int out_size, void* d_ws, size_t ws_size,
                              hipStream_t stream) {
    const float* x   = (const float*)d_in[0];
    const int*   ei  = (const int*)d_in[1];
    const float* w0  = (const float*)d_in[2];
    const float* b0  = (const float*)d_in[3];
    const float* w1  = (const float*)d_in[4];
    const float* b1  = (const float*)d_in[5];
    const float* w2  = (const float*)d_in[6];
    const float* b2  = (const float*)d_in[7];
    const float* fcw = (const float*)d_in[8];
    const float* fcb = (const float*)d_in[9];
    float* out = (float*)d_out;

    const int N = in_sizes[0] / DIN;
    const int E = in_sizes[1] / 2;
    const int* src = ei;
    const int* dst = ei + E;
    const int csr_cap = E + 8 * N + 8;

    char* p = (char*)d_ws;
    auto take = [&](size_t bytes) {
        char* q = p;
        p += (bytes + 255) & ~(size_t)255;
        return q;
    };
    int*    counts  = (int*)take((size_t)(N + 1) * 4);  // counts[N] = gtotal
    int*    gtotal  = counts + N;
    int*    offs    = (int*)take((size_t)N * 4);
    int*    cursor  = (int*)take((size_t)N * 4);
    float*  dinv    = (float*)take((size_t)N * 4);
    int*    csr_src = (int*)take((size_t)csr_cap * 4);
    __half* tbufA   = (__half*)take((size_t)(N + 1) * DH * 2);
    __half* tbufB   = (__half*)take((size_t)(N + 1) * DH * 2);

    hipMemsetAsync(counts, 0, (size_t)(N + 1) * 4, stream);

    deg_kernel<<<(E + 255) / 256, 256, 0, stream>>>(dst, counts, E);
    alloc_kernel<<<(N + 255) / 256, 256, 0, stream>>>(counts, gtotal, offs, cursor, dinv, N);
    fill_kernel<<<(csr_cap + 255) / 256, 256, 0, stream>>>(csr_src, N, csr_cap);
    int winSize = (N + NWIN - 1) / NWIN;
    scatter_kernel<<<1024, 256, 0, stream>>>(src, dst, cursor, csr_src, E, winSize);

    int node_grid = (N + 7) / 8;   // half-wave per node, 8 nodes/block
    int nTiles = (N + 15) / 16;

    mm128_mfma<<<(nTiles + 3) / 4, 256, 0, stream>>>(x, w0, dinv, tbufA, N, nTiles);
    aggmm_kernel<<<node_grid, 256, 0, stream>>>(tbufA, offs, counts, csr_src,
                                                dinv, b0, w1, tbufB, N);
    aggmm_kernel<<<node_grid, 256, 0, stream>>>(tbufB, offs, counts, csr_src,
                                                dinv, b1, w2, tbufA, N);
    aggfc_kernel<<<node_grid, 256, 0, stream>>>(tbufA, offs, counts, csr_src,
                                                dinv, b2, fcw, fcb, out, N);
}